// Round 7
// baseline (563.227 us; speedup 1.0000x reference)
//
#include <hip/hip_runtime.h>
#include <hip/hip_bf16.h>
#include <cstddef>

#define T_DIM 2048
#define B_DIM 64
#define I_DIM 128
#define H_DIM 128
#define FC_DIM 32
#define O_DIM 2

#define NC 32                // time chunks (parallel affine scan); 1 chunk/block
#define TC (T_DIM / NC)      // 64 timesteps per chunk
#define MT 4                 // 4 m-tiles of 16 t per chunk
#define SUBT (TC / 4)        // 16 timesteps per quad sub-chunk

#define NLOG2E  (-1.44269504088896f)
#define NLOG2E2 (-2.88539008177793f)

typedef __attribute__((ext_vector_type(8))) short bf16x8;
typedef __attribute__((ext_vector_type(4))) float f32x4;

// packed scaled fp32x8 -> bf16x8 (RNE) via v_cvt_pk_bf16_f32
__device__ __forceinline__ bf16x8 cvt8s(float4 u0, float4 u1, float s) {
    union { bf16x8 v; __hip_bfloat162 h2[4]; } u;
    float a[8] = {u0.x * s, u0.y * s, u0.z * s, u0.w * s,
                  u1.x * s, u1.y * s, u1.z * s, u1.w * s};
#pragma unroll
    for (int j = 0; j < 4; ++j) {
        float2 f2 = {a[2 * j], a[2 * j + 1]};
        u.h2[j] = __float22bfloat162_rn(f2);
    }
    return u.v;
}

// Single fused kernel: one block per (b, chunk), 8 waves covering all 128 h.
//  - weight fragments converted in-kernel from fp32, pre-scaled by -log2e
//    (g by -2*log2e) so activations are pure exp2/rcp with no negate.
//  - Phase A: 2 waves per m-tile convert the chunk's x slice into bf16 MFMA
//    A-fragments in LDS (lane-contiguous 16B slots, conflict-free b128).
//  - Phase B: per m-tile: 4 ds_read_b128, 12 MFMA, activations, per-quad
//    affine scan; cross-quad combine -> per-chunk (F,A) written with
//    agent-scope atomic stores.
//  - Last block per b (device-scope counter) folds the NC chunk affines,
//    computes o-gate at t=T-1, classifier, log_softmax.
// m-row -> t map within chunk: t(m) = (m>>2)*SUBT + mt*4 + (m&3); D rows
// (row = quad*4 + r) -> t = quad*SUBT + mt*4 + r.
__global__ __launch_bounds__(512, 4)
void gates_scan_fused_kernel(const float* __restrict__ x,
    const float* __restrict__ w_ig, const float* __restrict__ w_ii,
    const float* __restrict__ w_if,
    const float* __restrict__ b_g, const float* __restrict__ b_i,
    const float* __restrict__ b_f,
    const float* __restrict__ w_io, const float* __restrict__ b_o,
    const float* __restrict__ fc1_w, const float* __restrict__ fc1_b,
    const float* __restrict__ fc2_w, const float* __restrict__ fc2_b,
    float* __restrict__ wsF, float* __restrict__ wsA,
    int* __restrict__ counters, float* __restrict__ out)
{
    // frag[mt][kk][lane][8 shorts] = 4*4*64*8 shorts = 16 KB
    __shared__ short frag[MT * 4 * 64 * 8];
    __shared__ float hf[H_DIM];
    __shared__ float z1[FC_DIM];
    __shared__ int isLast;

    const int L    = threadIdx.x & 63;
    const int wv   = threadIdx.x >> 6;   // 0..7
    const int col  = L & 15;
    const int quad = L >> 4;
    const int bid  = blockIdx.x;
    const int b     = bid & (B_DIM - 1); // b-minor: same-b blocks 64 apart -> same XCD
    const int chunk = bid >> 6;

    // ---- weight fragments for this wave's 16 h columns: h = wv*16 + col
    const int h = wv * 16 + col;
    bf16x8 Bg[4], Bi[4], Bf[4];
    {
        const size_t wo = ((size_t)b * H_DIM + h) * I_DIM + quad * 8;
#pragma unroll
        for (int kk = 0; kk < 4; ++kk) {
            float4 g0 = *(const float4*)(w_ig + wo + kk * 32);
            float4 g1 = *(const float4*)(w_ig + wo + kk * 32 + 4);
            float4 i0 = *(const float4*)(w_ii + wo + kk * 32);
            float4 i1 = *(const float4*)(w_ii + wo + kk * 32 + 4);
            float4 f0 = *(const float4*)(w_if + wo + kk * 32);
            float4 f1 = *(const float4*)(w_if + wo + kk * 32 + 4);
            Bg[kk] = cvt8s(g0, g1, NLOG2E2);
            Bi[kk] = cvt8s(i0, i1, NLOG2E);
            Bf[kk] = cvt8s(f0, f1, NLOG2E);
        }
    }
    const float biasg = b_g[b * H_DIM + h] * NLOG2E2;
    const float biasi = b_i[b * H_DIM + h] * NLOG2E;
    const float biasf = b_f[b * H_DIM + h] * NLOG2E;

    // ---- Phase A: 2 waves per m-tile (each wave converts 2 k-slices)
    {
        const int amt = wv & 3;
        const int ak0 = (wv >> 2) * 2;
        const int atl = (col >> 2) * SUBT + amt * 4 + (col & 3);  // t within chunk
        const float* xp = x + ((size_t)(chunk * TC + atl) * B_DIM + b) * I_DIM;
#pragma unroll
        for (int kx = 0; kx < 2; ++kx) {
            const int kk = ak0 + kx;
            const int i0 = quad * 8 + kk * 32;
            float4 u0 = *(const float4*)(xp + i0);
            float4 u1 = *(const float4*)(xp + i0 + 4);
            *(bf16x8*)(frag + (((amt * 4 + kk) * 64) + L) * 8) = cvt8s(u0, u1, 1.0f);
        }
    }
    __syncthreads();

    // ---- Phase B: MFMA + activations + per-quad scan
    float Fq = 1.0f, Aq = 0.0f;
#pragma unroll
    for (int mt = 0; mt < MT; ++mt) {
        bf16x8 ah[4];
#pragma unroll
        for (int kk = 0; kk < 4; ++kk)
            ah[kk] = *(const bf16x8*)(frag + (((mt * 4 + kk) * 64) + L) * 8);
        f32x4 accg = {0.f, 0.f, 0.f, 0.f};
        f32x4 acci = {0.f, 0.f, 0.f, 0.f};
        f32x4 accf = {0.f, 0.f, 0.f, 0.f};
#pragma unroll
        for (int kk = 0; kk < 4; ++kk) {
            accg = __builtin_amdgcn_mfma_f32_16x16x32_bf16(ah[kk], Bg[kk], accg, 0, 0, 0);
            acci = __builtin_amdgcn_mfma_f32_16x16x32_bf16(ah[kk], Bi[kk], acci, 0, 0, 0);
            accf = __builtin_amdgcn_mfma_f32_16x16x32_bf16(ah[kk], Bf[kk], accf, 0, 0, 0);
        }
        // D row = quad*4 + r -> t = quad*SUBT + mt*4 + r (consecutive per quad)
#pragma unroll
        for (int r = 0; r < 4; ++r) {
            // weights pre-scaled by -log2e (g by -2log2e):
            //   eg = exp(-2p_g), ei = exp(-p_i), ef = exp(-p_f)
            float eg = __builtin_amdgcn_exp2f(accg[r] + biasg);
            float ei = __builtin_amdgcn_exp2f(acci[r] + biasi);
            float ef = __builtin_amdgcn_exp2f(accf[r] + biasf);
            float g  = 2.0f * __builtin_amdgcn_rcpf(1.0f + eg) - 1.0f;
            float iv = __builtin_amdgcn_rcpf(1.0f + ei);
            float fv = __builtin_amdgcn_rcpf(1.0f + ef);
            Aq = fv * Aq + iv * g;
            Fq = fv * Fq;
        }
    }

    // Ordered cross-quad combine (quad q covers t-range q*SUBT..): 2 rounds.
    float Fo = __shfl_xor(Fq, 16, 64);
    float Ao = __shfl_xor(Aq, 16, 64);
    if ((quad & 1) == 0) { Aq = Fo * Aq + Ao; Fq = Fo * Fq; }
    else                 { Aq = Fq * Ao + Aq; Fq = Fq * Fo; }
    Fo = __shfl_xor(Fq, 32, 64);
    Ao = __shfl_xor(Aq, 32, 64);
    if (quad < 2) { Aq = Fo * Aq + Ao; Fq = Fo * Fq; }
    else          { Aq = Fq * Ao + Aq; Fq = Fq * Fo; }

    if (quad == 0) {
        const int idx = (b * NC + chunk) * H_DIM + h;
        __hip_atomic_store(&wsF[idx], Fq, __ATOMIC_RELAXED, __HIP_MEMORY_SCOPE_AGENT);
        __hip_atomic_store(&wsA[idx], Aq, __ATOMIC_RELAXED, __HIP_MEMORY_SCOPE_AGENT);
    }

    // ---- fused finish: last block of this b folds and classifies
    __threadfence();      // release our ws stores device-wide
    __syncthreads();      // all waves of this block done (incl. their fences)
    if (threadIdx.x == 0)
        isLast = (atomicAdd(&counters[b], 1) == NC - 1);
    __syncthreads();
    if (isLast) {
        __threadfence();  // acquire: see all 31 other blocks' ws stores
        const int t = threadIdx.x;
        if (t < H_DIM) {
            float c = 0.0f;
#pragma unroll
            for (int nc = 0; nc < NC; ++nc) {
                const int idx = (b * NC + nc) * H_DIM + t;
                float F = __hip_atomic_load(&wsF[idx], __ATOMIC_RELAXED, __HIP_MEMORY_SCOPE_AGENT);
                float A = __hip_atomic_load(&wsA[idx], __ATOMIC_RELAXED, __HIP_MEMORY_SCOPE_AGENT);
                c = F * c + A;
            }
            const float* xl = x + ((size_t)(T_DIM - 1) * B_DIM + b) * I_DIM;
            const float* wo = w_io + ((size_t)b * H_DIM + t) * I_DIM;
            float acc = b_o[b * H_DIM + t];
#pragma unroll 8
            for (int i = 0; i < I_DIM; i += 4) {
                float4 xa = *(const float4*)(xl + i);
                float4 wa = *(const float4*)(wo + i);
                acc += xa.x * wa.x + xa.y * wa.y + xa.z * wa.z + xa.w * wa.w;
            }
            const float o = 1.0f / (1.0f + expf(-acc));
            hf[t] = o * tanhf(c);
        }
        __syncthreads();
        if (t < FC_DIM) {
            float a = fc1_b[t];
            const float* w1 = fc1_w + t * H_DIM;
            for (int i = 0; i < H_DIM; ++i) a += w1[i] * hf[i];
            z1[t] = tanhf(a);
        }
        __syncthreads();
        if (t == 0) {
            float z0 = fc2_b[0], zo1 = fc2_b[1];
            for (int j = 0; j < FC_DIM; ++j) {
                z0  += fc2_w[j] * z1[j];
                zo1 += fc2_w[FC_DIM + j] * z1[j];
            }
            const float m = fmaxf(z0, zo1);
            const float lse = m + logf(expf(z0 - m) + expf(zo1 - m));
            out[b * O_DIM + 0] = z0 - lse;
            out[b * O_DIM + 1] = zo1 - lse;
        }
    }
}

extern "C" void kernel_launch(void* const* d_in, const int* in_sizes, int n_in,
                              void* d_out, int out_size, void* d_ws, size_t ws_size,
                              hipStream_t stream) {
    const float* x     = (const float*)d_in[0];
    const float* w_ig  = (const float*)d_in[1];
    const float* w_ii  = (const float*)d_in[2];
    const float* w_if  = (const float*)d_in[3];
    const float* w_io  = (const float*)d_in[4];
    // d_in[5..8] = w_hg/w_hi/w_hf/w_ho multiply a zero hidden state -> skipped
    const float* b_g   = (const float*)d_in[9];
    const float* b_i   = (const float*)d_in[10];
    const float* b_f   = (const float*)d_in[11];
    const float* b_o   = (const float*)d_in[12];
    const float* fc1_w = (const float*)d_in[13];
    const float* fc1_b = (const float*)d_in[14];
    const float* fc2_w = (const float*)d_in[15];
    const float* fc2_b = (const float*)d_in[16];

    // Workspace: wsF (1 MB) + wsA (1 MB) + counters (256 B)
    const size_t NWS = (size_t)B_DIM * NC * H_DIM;   // 262144 floats
    float* wsF = (float*)d_ws;
    float* wsA = wsF + NWS;
    int* counters = (int*)(wsA + NWS);
    float* out = (float*)d_out;

    hipMemsetAsync(counters, 0, B_DIM * sizeof(int), stream);

    // bid = chunk*64 + b (b-minor => per-b weight L2 reuse within an XCD)
    gates_scan_fused_kernel<<<dim3(B_DIM * NC), 512, 0, stream>>>(
        x, w_ig, w_ii, w_if, b_g, b_i, b_f,
        w_io, b_o, fc1_w, fc1_b, fc2_w, fc2_b,
        wsF, wsA, counters, out);
}

// Round 8
// 200.604 us; speedup vs baseline: 2.8077x; 2.8077x over previous
//
#include <hip/hip_runtime.h>
#include <hip/hip_bf16.h>
#include <cstddef>

#define T_DIM 2048
#define B_DIM 64
#define I_DIM 128
#define H_DIM 128
#define FC_DIM 32
#define O_DIM 2

#define NC 64                // time chunks (parallel affine scan); 1 chunk/block
#define TC (T_DIM / NC)      // 32 timesteps per chunk
#define MT 2                 // 2 m-tiles of 16 t per chunk
#define SUBT (TC / 4)        // 8 timesteps per quad sub-chunk

#define NLOG2E  (-1.44269504088896f)
#define NLOG2E2 (-2.88539008177793f)

typedef __attribute__((ext_vector_type(8))) short bf16x8;
typedef __attribute__((ext_vector_type(4))) float f32x4;

// packed scaled fp32x8 -> bf16x8 (RNE) via v_cvt_pk_bf16_f32
__device__ __forceinline__ bf16x8 cvt8s(float4 u0, float4 u1, float s) {
    union { bf16x8 v; __hip_bfloat162 h2[4]; } u;
    float a[8] = {u0.x * s, u0.y * s, u0.z * s, u0.w * s,
                  u1.x * s, u1.y * s, u1.z * s, u1.w * s};
#pragma unroll
    for (int j = 0; j < 4; ++j) {
        float2 f2 = {a[2 * j], a[2 * j + 1]};
        u.h2[j] = __float22bfloat162_rn(f2);
    }
    return u.v;
}

// Pass 0: gate weights fp32 -> bf16, pre-scaled by -log2e (g by -2*log2e) so
// the gates kernel uses exp2 with no negate. Layout preserved [b][h][i].
__global__ void convert_w_kernel(const float* __restrict__ wg,
                                 const float* __restrict__ wi,
                                 const float* __restrict__ wf,
                                 short* __restrict__ og,
                                 short* __restrict__ oi,
                                 short* __restrict__ of)
{
    const float* src = (blockIdx.y == 0) ? wg : (blockIdx.y == 1) ? wi : wf;
    short* dst       = (blockIdx.y == 0) ? og : (blockIdx.y == 1) ? oi : of;
    const float scale = (blockIdx.y == 0) ? NLOG2E2 : NLOG2E;
    const size_t idx = ((size_t)blockIdx.x * 256 + threadIdx.x) * 8;
    float4 u0 = *(const float4*)(src + idx);
    float4 u1 = *(const float4*)(src + idx + 4);
    *(bf16x8*)(dst + idx) = cvt8s(u0, u1, scale);
}

// Pass 1: one block per (b, chunk), 8 waves covering all 128 h.
// Phase A: 1 wave per (m-tile, k-slice) converts the chunk's x slice (fp32,
//          read once) into bf16 MFMA A-fragments in LDS (lane-contiguous
//          16B slots -> conflict-free b128 writes & reads).
// Phase B: per m-tile: 2x ds_read_b128 x2, 6 MFMA... (MT=2: per tile 4
//          ds_read_b128, 12 MFMA), activations (bias pre-loaded into the
//          accumulator init), per-quad affine scan; cross-quad combine.
// m-row -> t map within chunk: t(m) = (m>>2)*SUBT + mt*4 + (m&3); D rows
// (row = quad*4 + r) -> t = quad*SUBT + mt*4 + r (ascending per quad).
__global__ __launch_bounds__(512, 4)
void gates_scan_kernel(const float* __restrict__ x,
    const short* __restrict__ wg, const short* __restrict__ wi,
    const short* __restrict__ wf,
    const float* __restrict__ b_g, const float* __restrict__ b_i,
    const float* __restrict__ b_f,
    float* __restrict__ wsF, float* __restrict__ wsA)
{
    // frag[mt][kk][lane][8 shorts] = 2*4*64*8 shorts = 8 KB
    __shared__ short frag[MT * 4 * 64 * 8];

    const int L    = threadIdx.x & 63;
    const int wv   = threadIdx.x >> 6;   // 0..7
    const int col  = L & 15;
    const int quad = L >> 4;
    const int bid  = blockIdx.x;
    const int b     = bid & (B_DIM - 1); // b-minor: same-b blocks 64 apart -> same XCD
    const int chunk = bid >> 6;

    // ---- weight fragments for this wave's 16 h columns: h = wv*16 + col
    const int h = wv * 16 + col;
    bf16x8 Bg[4], Bi[4], Bf[4];
    {
        const size_t wo = ((size_t)b * H_DIM + h) * I_DIM + quad * 8;
#pragma unroll
        for (int kk = 0; kk < 4; ++kk) {
            Bg[kk] = *(const bf16x8*)(wg + wo + kk * 32);
            Bi[kk] = *(const bf16x8*)(wi + wo + kk * 32);
            Bf[kk] = *(const bf16x8*)(wf + wo + kk * 32);
        }
    }
    const float biasg = b_g[b * H_DIM + h] * NLOG2E2;
    const float biasi = b_i[b * H_DIM + h] * NLOG2E;
    const float biasf = b_f[b * H_DIM + h] * NLOG2E;

    // ---- Phase A: wave wv converts m-tile (wv>>2), k-slice (wv&3)
    {
        const int amt = wv >> 2;          // 0..1
        const int akk = wv & 3;           // 0..3
        const int atl = (col >> 2) * SUBT + amt * 4 + (col & 3);  // t within chunk
        const float* xp = x + ((size_t)(chunk * TC + atl) * B_DIM + b) * I_DIM;
        const int i0 = quad * 8 + akk * 32;
        float4 u0 = *(const float4*)(xp + i0);
        float4 u1 = *(const float4*)(xp + i0 + 4);
        *(bf16x8*)(frag + (((amt * 4 + akk) * 64) + L) * 8) = cvt8s(u0, u1, 1.0f);
    }
    __syncthreads();

    // ---- Phase B: MFMA (acc pre-init to bias) + activations + per-quad scan
    float Fq = 1.0f, Aq = 0.0f;
#pragma unroll
    for (int mt = 0; mt < MT; ++mt) {
        bf16x8 ah[4];
#pragma unroll
        for (int kk = 0; kk < 4; ++kk)
            ah[kk] = *(const bf16x8*)(frag + (((mt * 4 + kk) * 64) + L) * 8);
        // D col = lane&15 = h is lane-uniform -> bias folds into acc init
        f32x4 accg = {biasg, biasg, biasg, biasg};
        f32x4 acci = {biasi, biasi, biasi, biasi};
        f32x4 accf = {biasf, biasf, biasf, biasf};
#pragma unroll
        for (int kk = 0; kk < 4; ++kk) {
            accg = __builtin_amdgcn_mfma_f32_16x16x32_bf16(ah[kk], Bg[kk], accg, 0, 0, 0);
            acci = __builtin_amdgcn_mfma_f32_16x16x32_bf16(ah[kk], Bi[kk], acci, 0, 0, 0);
            accf = __builtin_amdgcn_mfma_f32_16x16x32_bf16(ah[kk], Bf[kk], accf, 0, 0, 0);
        }
        // D row = quad*4 + r -> t = quad*SUBT + mt*4 + r (consecutive per quad)
#pragma unroll
        for (int r = 0; r < 4; ++r) {
            // weights pre-scaled by -log2e (g by -2log2e):
            float eg = __builtin_amdgcn_exp2f(accg[r]);  // exp(-2 p_g)
            float ei = __builtin_amdgcn_exp2f(acci[r]);  // exp(-p_i)
            float ef = __builtin_amdgcn_exp2f(accf[r]);  // exp(-p_f)
            float g  = 2.0f * __builtin_amdgcn_rcpf(1.0f + eg) - 1.0f;
            float iv = __builtin_amdgcn_rcpf(1.0f + ei);
            float fv = __builtin_amdgcn_rcpf(1.0f + ef);
            Aq = fv * Aq + iv * g;
            Fq = fv * Fq;
        }
    }

    // Ordered cross-quad combine (quad q covers t-range q*SUBT..): 2 rounds.
    float Fo = __shfl_xor(Fq, 16, 64);
    float Ao = __shfl_xor(Aq, 16, 64);
    if ((quad & 1) == 0) { Aq = Fo * Aq + Ao; Fq = Fo * Fq; }
    else                 { Aq = Fq * Ao + Aq; Fq = Fq * Fo; }
    Fo = __shfl_xor(Fq, 32, 64);
    Ao = __shfl_xor(Aq, 32, 64);
    if (quad < 2) { Aq = Fo * Aq + Ao; Fq = Fo * Fq; }
    else          { Aq = Fq * Ao + Aq; Fq = Fq * Fo; }

    if (quad == 0) {
        const int idx = (b * NC + chunk) * H_DIM + h;
        wsF[idx] = Fq;
        wsA[idx] = Aq;
    }
}

// Pass 2: fold NC chunk-affines -> c_fin; o-gate at t=T-1 (fp32 dot);
// h_fin = o*tanh(c); classifier + log_softmax. One block per batch.
__global__ void finish_kernel(const float* __restrict__ x,
    const float* __restrict__ w_io, const float* __restrict__ b_o,
    const float* __restrict__ fc1_w, const float* __restrict__ fc1_b,
    const float* __restrict__ fc2_w, const float* __restrict__ fc2_b,
    const float* __restrict__ wsF, const float* __restrict__ wsA,
    float* __restrict__ out)
{
    const int b = blockIdx.x;
    const int h = threadIdx.x;  // 128 threads
    __shared__ float hf[H_DIM];
    __shared__ float z1[FC_DIM];

    float c = 0.0f;
#pragma unroll
    for (int nc = 0; nc < NC; ++nc) {
        const int idx = (b * NC + nc) * H_DIM + h;
        c = wsF[idx] * c + wsA[idx];
    }
    const float* xl = x + ((size_t)(T_DIM - 1) * B_DIM + b) * I_DIM;
    const float* wo = w_io + ((size_t)b * H_DIM + h) * I_DIM;
    float acc = b_o[b * H_DIM + h];
#pragma unroll 8
    for (int i = 0; i < I_DIM; i += 4) {
        float4 xa = *(const float4*)(xl + i);
        float4 wa = *(const float4*)(wo + i);
        acc += xa.x * wa.x + xa.y * wa.y + xa.z * wa.z + xa.w * wa.w;
    }
    const float o = 1.0f / (1.0f + expf(-acc));
    hf[h] = o * tanhf(c);
    __syncthreads();

    if (h < FC_DIM) {
        float a = fc1_b[h];
        const float* w1 = fc1_w + h * H_DIM;
        for (int i = 0; i < H_DIM; ++i) a += w1[i] * hf[i];
        z1[h] = tanhf(a);
    }
    __syncthreads();

    if (h == 0) {
        float z0 = fc2_b[0], zo1 = fc2_b[1];
        for (int j = 0; j < FC_DIM; ++j) {
            z0  += fc2_w[j] * z1[j];
            zo1 += fc2_w[FC_DIM + j] * z1[j];
        }
        const float m = fmaxf(z0, zo1);
        const float lse = m + logf(expf(z0 - m) + expf(zo1 - m));
        out[b * O_DIM + 0] = z0 - lse;
        out[b * O_DIM + 1] = zo1 - lse;
    }
}

extern "C" void kernel_launch(void* const* d_in, const int* in_sizes, int n_in,
                              void* d_out, int out_size, void* d_ws, size_t ws_size,
                              hipStream_t stream) {
    const float* x     = (const float*)d_in[0];
    const float* w_ig  = (const float*)d_in[1];
    const float* w_ii  = (const float*)d_in[2];
    const float* w_if  = (const float*)d_in[3];
    const float* w_io  = (const float*)d_in[4];
    // d_in[5..8] = w_hg/w_hi/w_hf/w_ho multiply a zero hidden state -> skipped
    const float* b_g   = (const float*)d_in[9];
    const float* b_i   = (const float*)d_in[10];
    const float* b_f   = (const float*)d_in[11];
    const float* b_o   = (const float*)d_in[12];
    const float* fc1_w = (const float*)d_in[13];
    const float* fc1_b = (const float*)d_in[14];
    const float* fc2_w = (const float*)d_in[15];
    const float* fc2_b = (const float*)d_in[16];

    // Workspace: wg/wi/wf bf16 (3 x 2 MB) + wsF/wsA (2 x 2 MB)
    const size_t NW = (size_t)B_DIM * H_DIM * I_DIM;    // 1,048,576
    short* wgc = (short*)d_ws;
    short* wic = wgc + NW;
    short* wfc = wic + NW;
    float* wsF = (float*)(wfc + NW);
    float* wsA = wsF + (size_t)B_DIM * NC * H_DIM;
    float* out = (float*)d_out;

    convert_w_kernel<<<dim3(NW / (256 * 8), 3), 256, 0, stream>>>(
        w_ig, w_ii, w_if, wgc, wic, wfc);

    // bid = chunk*64 + b (b-minor => per-b weight L2 reuse within an XCD)
    gates_scan_kernel<<<dim3(B_DIM * NC), 512, 0, stream>>>(
        x, wgc, wic, wfc, b_g, b_i, b_f, wsF, wsA);

    finish_kernel<<<B_DIM, 128, 0, stream>>>(x, w_io, b_o, fc1_w, fc1_b,
                                             fc2_w, fc2_b, wsF, wsA, out);
}

// Round 9
// 169.941 us; speedup vs baseline: 3.3142x; 1.1804x over previous
//
#include <hip/hip_runtime.h>
#include <hip/hip_bf16.h>
#include <cstddef>

#define T_DIM 2048
#define B_DIM 64
#define I_DIM 128
#define H_DIM 128
#define FC_DIM 32
#define O_DIM 2

#define NC 32                // time chunks (parallel affine scan); optimum (R4 vs R3/R8)
#define TC (T_DIM / NC)      // 64 timesteps per chunk
#define MT 4                 // 4 m-tiles of 16 t per chunk
#define SUBT (TC / 4)        // 16 timesteps per quad sub-chunk

#define NLOG2E  (-1.44269504088896f)
#define NLOG2E2 (-2.88539008177793f)

typedef __attribute__((ext_vector_type(8))) short bf16x8;
typedef __attribute__((ext_vector_type(4))) float f32x4;

// packed scaled fp32x8 -> bf16x8 (RNE) via v_cvt_pk_bf16_f32
__device__ __forceinline__ bf16x8 cvt8s(float4 u0, float4 u1, float s) {
    union { bf16x8 v; __hip_bfloat162 h2[4]; } u;
    float a[8] = {u0.x * s, u0.y * s, u0.z * s, u0.w * s,
                  u1.x * s, u1.y * s, u1.z * s, u1.w * s};
#pragma unroll
    for (int j = 0; j < 4; ++j) {
        float2 f2 = {a[2 * j], a[2 * j + 1]};
        u.h2[j] = __float22bfloat162_rn(f2);
    }
    return u.v;
}

// Pass 0: gate weights fp32 -> bf16, pre-scaled by -log2e (g by -2*log2e) so
// the gates kernel uses exp2 with no negate. Layout preserved [b][h][i].
__global__ void convert_w_kernel(const float* __restrict__ wg,
                                 const float* __restrict__ wi,
                                 const float* __restrict__ wf,
                                 short* __restrict__ og,
                                 short* __restrict__ oi,
                                 short* __restrict__ of)
{
    const float* src = (blockIdx.y == 0) ? wg : (blockIdx.y == 1) ? wi : wf;
    short* dst       = (blockIdx.y == 0) ? og : (blockIdx.y == 1) ? oi : of;
    const float scale = (blockIdx.y == 0) ? NLOG2E2 : NLOG2E;
    const size_t idx = ((size_t)blockIdx.x * 256 + threadIdx.x) * 8;
    float4 u0 = *(const float4*)(src + idx);
    float4 u1 = *(const float4*)(src + idx + 4);
    *(bf16x8*)(dst + idx) = cvt8s(u0, u1, scale);
}

// Pass 1: one block per (b, h-half, chunk): 256 threads = 4 waves, each wave
// owns 16 h columns of its 64-h half. 4 independent barrier domains per CU.
// Phase A: wave wv converts m-tile wv of the chunk's x slice into bf16 MFMA
//          A-fragments in LDS (lane-contiguous 16B slots, conflict-free b128).
//          Fragments depend only on lane -> shared by all h-waves.
// Phase B: per m-tile: 4 ds_read_b128, 12 MFMA (bias pre-loaded into the
//          accumulator init), exp2 activations, per-quad affine scan;
//          cross-quad ordered combine at end.
// m-row -> t map within chunk: t(m) = (m>>2)*SUBT + mt*4 + (m&3); D rows
// (row = quad*4 + r) -> t = quad*SUBT + mt*4 + r (ascending per quad).
__global__ __launch_bounds__(256, 4)
void gates_scan_kernel(const float* __restrict__ x,
    const short* __restrict__ wg, const short* __restrict__ wi,
    const short* __restrict__ wf,
    const float* __restrict__ b_g, const float* __restrict__ b_i,
    const float* __restrict__ b_f,
    float* __restrict__ wsF, float* __restrict__ wsA)
{
    // frag[mt][kk][lane][8 shorts] = 4*4*64*8 shorts = 16 KB
    __shared__ short frag[MT * 4 * 64 * 8];

    const int L    = threadIdx.x & 63;
    const int wv   = threadIdx.x >> 6;   // 0..3
    const int col  = L & 15;
    const int quad = L >> 4;
    const int bid  = blockIdx.x;
    const int half  = bid & 1;
    const int b     = (bid >> 1) & (B_DIM - 1);  // b near-minor -> weight L2 reuse per XCD
    const int chunk = bid >> 7;

    // ---- weight fragments for this wave's 16 h columns
    const int h = half * 64 + wv * 16 + col;
    bf16x8 Bg[4], Bi[4], Bf[4];
    {
        const size_t wo = ((size_t)b * H_DIM + h) * I_DIM + quad * 8;
#pragma unroll
        for (int kk = 0; kk < 4; ++kk) {
            Bg[kk] = *(const bf16x8*)(wg + wo + kk * 32);
            Bi[kk] = *(const bf16x8*)(wi + wo + kk * 32);
            Bf[kk] = *(const bf16x8*)(wf + wo + kk * 32);
        }
    }
    const float biasg = b_g[b * H_DIM + h] * NLOG2E2;
    const float biasi = b_i[b * H_DIM + h] * NLOG2E;
    const float biasf = b_f[b * H_DIM + h] * NLOG2E;

    // ---- Phase A: wave wv converts m-tile mt = wv (4 k-slices each)
    {
        const int amt = wv;
        const int atl = (col >> 2) * SUBT + amt * 4 + (col & 3);  // t within chunk
        const float* xp = x + ((size_t)(chunk * TC + atl) * B_DIM + b) * I_DIM;
#pragma unroll
        for (int kk = 0; kk < 4; ++kk) {
            const int i0 = quad * 8 + kk * 32;
            float4 u0 = *(const float4*)(xp + i0);
            float4 u1 = *(const float4*)(xp + i0 + 4);
            *(bf16x8*)(frag + (((amt * 4 + kk) * 64) + L) * 8) = cvt8s(u0, u1, 1.0f);
        }
    }
    __syncthreads();

    // ---- Phase B: MFMA (acc pre-init to bias) + activations + per-quad scan
    float Fq = 1.0f, Aq = 0.0f;
#pragma unroll
    for (int mt = 0; mt < MT; ++mt) {
        bf16x8 ah[4];
#pragma unroll
        for (int kk = 0; kk < 4; ++kk)
            ah[kk] = *(const bf16x8*)(frag + (((mt * 4 + kk) * 64) + L) * 8);
        // D col = lane&15 = h is lane-uniform -> bias folds into acc init
        f32x4 accg = {biasg, biasg, biasg, biasg};
        f32x4 acci = {biasi, biasi, biasi, biasi};
        f32x4 accf = {biasf, biasf, biasf, biasf};
#pragma unroll
        for (int kk = 0; kk < 4; ++kk) {
            accg = __builtin_amdgcn_mfma_f32_16x16x32_bf16(ah[kk], Bg[kk], accg, 0, 0, 0);
            acci = __builtin_amdgcn_mfma_f32_16x16x32_bf16(ah[kk], Bi[kk], acci, 0, 0, 0);
            accf = __builtin_amdgcn_mfma_f32_16x16x32_bf16(ah[kk], Bf[kk], accf, 0, 0, 0);
        }
        // D row = quad*4 + r -> t = quad*SUBT + mt*4 + r (consecutive per quad)
#pragma unroll
        for (int r = 0; r < 4; ++r) {
            // weights pre-scaled by -log2e (g by -2log2e):
            float eg = __builtin_amdgcn_exp2f(accg[r]);  // exp(-2 p_g)
            float ei = __builtin_amdgcn_exp2f(acci[r]);  // exp(-p_i)
            float ef = __builtin_amdgcn_exp2f(accf[r]);  // exp(-p_f)
            float g  = 2.0f * __builtin_amdgcn_rcpf(1.0f + eg) - 1.0f;
            float iv = __builtin_amdgcn_rcpf(1.0f + ei);
            float fv = __builtin_amdgcn_rcpf(1.0f + ef);
            Aq = fv * Aq + iv * g;
            Fq = fv * Fq;
        }
    }

    // Ordered cross-quad combine (quad q covers t-range q*SUBT..): 2 rounds.
    float Fo = __shfl_xor(Fq, 16, 64);
    float Ao = __shfl_xor(Aq, 16, 64);
    if ((quad & 1) == 0) { Aq = Fo * Aq + Ao; Fq = Fo * Fq; }
    else                 { Aq = Fq * Ao + Aq; Fq = Fq * Fo; }
    Fo = __shfl_xor(Fq, 32, 64);
    Ao = __shfl_xor(Aq, 32, 64);
    if (quad < 2) { Aq = Fo * Aq + Ao; Fq = Fo * Fq; }
    else          { Aq = Fq * Ao + Aq; Fq = Fq * Fo; }

    if (quad == 0) {
        const int idx = (b * NC + chunk) * H_DIM + h;
        wsF[idx] = Fq;
        wsA[idx] = Aq;
    }
}

// Pass 2: fold NC chunk-affines -> c_fin; o-gate at t=T-1 (fp32 dot);
// h_fin = o*tanh(c); classifier + log_softmax. One block per batch.
__global__ void finish_kernel(const float* __restrict__ x,
    const float* __restrict__ w_io, const float* __restrict__ b_o,
    const float* __restrict__ fc1_w, const float* __restrict__ fc1_b,
    const float* __restrict__ fc2_w, const float* __restrict__ fc2_b,
    const float* __restrict__ wsF, const float* __restrict__ wsA,
    float* __restrict__ out)
{
    const int b = blockIdx.x;
    const int h = threadIdx.x;  // 128 threads
    __shared__ float hf[H_DIM];
    __shared__ float z1[FC_DIM];

    float c = 0.0f;
#pragma unroll
    for (int nc = 0; nc < NC; ++nc) {
        const int idx = (b * NC + nc) * H_DIM + h;
        c = wsF[idx] * c + wsA[idx];
    }
    const float* xl = x + ((size_t)(T_DIM - 1) * B_DIM + b) * I_DIM;
    const float* wo = w_io + ((size_t)b * H_DIM + h) * I_DIM;
    float acc = b_o[b * H_DIM + h];
#pragma unroll 8
    for (int i = 0; i < I_DIM; i += 4) {
        float4 xa = *(const float4*)(xl + i);
        float4 wa = *(const float4*)(wo + i);
        acc += xa.x * wa.x + xa.y * wa.y + xa.z * wa.z + xa.w * wa.w;
    }
    const float o = 1.0f / (1.0f + expf(-acc));
    hf[h] = o * tanhf(c);
    __syncthreads();

    if (h < FC_DIM) {
        float a = fc1_b[h];
        const float* w1 = fc1_w + h * H_DIM;
        for (int i = 0; i < H_DIM; ++i) a += w1[i] * hf[i];
        z1[h] = tanhf(a);
    }
    __syncthreads();

    if (h == 0) {
        float z0 = fc2_b[0], zo1 = fc2_b[1];
        for (int j = 0; j < FC_DIM; ++j) {
            z0  += fc2_w[j] * z1[j];
            zo1 += fc2_w[FC_DIM + j] * z1[j];
        }
        const float m = fmaxf(z0, zo1);
        const float lse = m + logf(expf(z0 - m) + expf(zo1 - m));
        out[b * O_DIM + 0] = z0 - lse;
        out[b * O_DIM + 1] = zo1 - lse;
    }
}

extern "C" void kernel_launch(void* const* d_in, const int* in_sizes, int n_in,
                              void* d_out, int out_size, void* d_ws, size_t ws_size,
                              hipStream_t stream) {
    const float* x     = (const float*)d_in[0];
    const float* w_ig  = (const float*)d_in[1];
    const float* w_ii  = (const float*)d_in[2];
    const float* w_if  = (const float*)d_in[3];
    const float* w_io  = (const float*)d_in[4];
    // d_in[5..8] = w_hg/w_hi/w_hf/w_ho multiply a zero hidden state -> skipped
    const float* b_g   = (const float*)d_in[9];
    const float* b_i   = (const float*)d_in[10];
    const float* b_f   = (const float*)d_in[11];
    const float* b_o   = (const float*)d_in[12];
    const float* fc1_w = (const float*)d_in[13];
    const float* fc1_b = (const float*)d_in[14];
    const float* fc2_w = (const float*)d_in[15];
    const float* fc2_b = (const float*)d_in[16];

    // Workspace: wg/wi/wf bf16 (3 x 2 MB) + wsF/wsA (2 x 1 MB)
    const size_t NW = (size_t)B_DIM * H_DIM * I_DIM;    // 1,048,576
    short* wgc = (short*)d_ws;
    short* wic = wgc + NW;
    short* wfc = wic + NW;
    float* wsF = (float*)(wfc + NW);
    float* wsA = wsF + (size_t)B_DIM * NC * H_DIM;
    float* out = (float*)d_out;

    convert_w_kernel<<<dim3(NW / (256 * 8), 3), 256, 0, stream>>>(
        w_ig, w_ii, w_if, wgc, wic, wfc);

    // bid = chunk*128 + b*2 + half; 4096 blocks of 256 thr -> ~4 resident
    // blocks/CU = 4 independent barrier domains interleaving PhaseA/PhaseB
    gates_scan_kernel<<<dim3(B_DIM * 2 * NC), 256, 0, stream>>>(
        x, wgc, wic, wfc, b_g, b_i, b_f, wsF, wsA);

    finish_kernel<<<B_DIM, 128, 0, stream>>>(x, w_io, b_o, fc1_w, fc1_b,
                                             fc2_w, fc2_b, wsF, wsA, out);
}